// Round 5
// baseline (431.705 us; speedup 1.0000x reference)
//
#include <hip/hip_runtime.h>
#include <math.h>
#include <stdint.h>

// Problem constants (fixed by the reference):
#define NQ 4096    // queries
#define MP 65536   // manifold points
#define DD 64      // dims
#define QT 64      // queries per block (2 nt tiles of 32)
#define STRIPES 8  // point stripes == XCDs (b&7 dispatch heuristic)
#define PPB (MP / STRIPES)      // 8192 points per stripe
#define GPS (PPB / 32)          // 256 groups (of 32 points) per stripe
#define PG32 (MP / 32)          // 2048 point groups
#define XG32 (NQ / 32)          // 128 query groups

typedef _Float16 f16;
typedef _Float16 f16x8 __attribute__((ext_vector_type(8)));
typedef float f32x4 __attribute__((ext_vector_type(4)));
typedef float f32x16 __attribute__((ext_vector_type(16)));

// Fragment-swizzled layout for 32x32x16 operands (per 32-row group g):
//   FR[((g*2 + sel)*4 + kseg)*512 + lane*8] : 8 f16 = 16 B per lane
//   sel 0=hi 1=lo ; kseg 0..3 (k = kseg*16 + (lane>>5)*8 + j) ; row = lane&31.
//   Group stride = 4096 f16 (8 KB).

// One-shot pre-swizzle: fp32 rows -> hi/lo fp16 fragment order; also 0.5*|p|^2.
// Tasks 0..2047 = P groups, 2048..2175 = X groups. One group per wave.
__global__ __launch_bounds__(256) void prep_k(const float* __restrict__ P,
                                              const float* __restrict__ X,
                                              f16* __restrict__ PF,
                                              f16* __restrict__ XF,
                                              float* __restrict__ pnh) {
    const int w = threadIdx.x >> 6, lane = threadIdx.x & 63;
    const int r32 = lane & 31, hw = lane >> 5;
    const int task = blockIdx.x * 4 + w;
    const float* src; f16* dst; int g; bool dopn;
    if (task < PG32) { src = P; dst = PF; g = task; dopn = true; }
    else             { src = X; dst = XF; g = task - PG32; dopn = false; }

    const float* row = src + ((size_t)g * 32 + r32) * DD;
    float ss = 0.f;
    #pragma unroll
    for (int ks = 0; ks < 4; ++ks) {
        const float* p0 = row + ks * 16 + hw * 8;
        float4 v0 = *reinterpret_cast<const float4*>(p0);
        float4 v1 = *reinterpret_cast<const float4*>(p0 + 4);
        float vv[8] = {v0.x, v0.y, v0.z, v0.w, v1.x, v1.y, v1.z, v1.w};
        f16x8 h, l;
        #pragma unroll
        for (int j = 0; j < 8; ++j) {
            f16 hh = (f16)vv[j];
            h[j] = hh;
            l[j] = (f16)(vv[j] - (float)hh);
            ss = fmaf(vv[j], vv[j], ss);
        }
        f16* base = dst + ((size_t)(g * 2 + 0) * 4 + ks) * 512 + lane * 8;
        *reinterpret_cast<f16x8*>(base) = h;          // hi
        *reinterpret_cast<f16x8*>(base + 2048) = l;   // lo (sel stride 4*512)
    }
    if (dopn) {
        ss += __shfl_xor(ss, 32);   // combine the two k-halves of this row
        if (hw == 0) pnh[g * 32 + r32] = 0.5f * ss;
    }
}

// Fused split-fp16 32x32x16 MFMA dot + argmin, zero LDS / zero barriers.
// score' = x.p - 0.5|p|^2 (maximize) ; x.p via ah*bh + ah*bl + al*bh.
// Block 256 = 4 waves; grid 512 = 64 qtiles x 8 stripes; stripe = b&7 pins the
// 2 MB PF stripe to one XCD's L2.
__global__ __launch_bounds__(256, 2) void argmin_k(const f16* __restrict__ PF,
                                                   const f16* __restrict__ XF,
                                                   const float* __restrict__ pnh,
                                                   unsigned long long* __restrict__ best) {
    const int t = threadIdx.x;
    const int lane = t & 63, w = t >> 6;
    const int c32 = lane & 31, hw = lane >> 5;
    const int b = blockIdx.x;
    const int stripe = b & 7;
    const int qt = b >> 3;
    const int qBase = qt * QT;

    // Query fragments (B operand), held in registers for the whole kernel.
    f16x8 QH[2][4], QL[2][4];
    #pragma unroll
    for (int nt = 0; nt < 2; ++nt)
        #pragma unroll
        for (int ks = 0; ks < 4; ++ks) {
            const f16* o = XF + ((size_t)((qt * 2 + nt) * 2 + 0) * 4 + ks) * 512 + lane * 8;
            QH[nt][ks] = *reinterpret_cast<const f16x8*>(o);
            QL[nt][ks] = *reinterpret_cast<const f16x8*>(o + 2048);
        }

    float rmax[2];
    int   ridx[2];
    #pragma unroll
    for (int nt = 0; nt < 2; ++nt) { rmax[nt] = -INFINITY; ridx[nt] = 0; }

    auto PROC = [&](int gg, f16x8* FH, f16x8* FL) {
        f32x4 pq[4];
        #pragma unroll
        for (int i = 0; i < 4; ++i)
            pq[i] = *reinterpret_cast<const f32x4*>(pnh + gg * 32 + i * 8 + hw * 4);
        #pragma unroll
        for (int nt = 0; nt < 2; ++nt) {
            f32x16 a = {0.f,0.f,0.f,0.f,0.f,0.f,0.f,0.f,0.f,0.f,0.f,0.f,0.f,0.f,0.f,0.f};
            #pragma unroll
            for (int ks = 0; ks < 4; ++ks) {
                a = __builtin_amdgcn_mfma_f32_32x32x16_f16(FH[ks], QH[nt][ks], a, 0, 0, 0);
                a = __builtin_amdgcn_mfma_f32_32x32x16_f16(FH[ks], QL[nt][ks], a, 0, 0, 0);
                a = __builtin_amdgcn_mfma_f32_32x32x16_f16(FL[ks], QH[nt][ks], a, 0, 0, 0);
            }
            // C/D: col=lane&31 (query), row=(reg&3)+8*(reg>>2)+4*hw (point).
            float s[16];
            #pragma unroll
            for (int r = 0; r < 16; ++r) s[r] = a[r] - pq[r >> 2][r & 3];
            float smax = s[0];
            #pragma unroll
            for (int r = 1; r < 16; ++r) smax = fmaxf(smax, s[r]);
            if (smax > rmax[nt]) {      // strict > keeps earliest (lowest) group
                rmax[nt] = smax;
                int rr = 15;            // descending chain -> lowest matching reg
                #pragma unroll
                for (int r = 14; r >= 0; --r) rr = (s[r] == smax) ? r : rr;
                ridx[nt] = gg * 32 + (rr & 3) + 8 * (rr >> 2) + 4 * hw;
            }
        }
    };

    // Double-buffered group loop: wave w covers groups stripe*GPS + w + 4*j.
    int g = stripe * GPS + w;
    f16x8 HA[4], LA[4], HB[4], LB[4];
    {
        const f16* f0 = PF + (size_t)g * 4096 + lane * 8;
        #pragma unroll
        for (int ks = 0; ks < 4; ++ks) {
            HA[ks] = *reinterpret_cast<const f16x8*>(f0 + ks * 512);
            LA[ks] = *reinterpret_cast<const f16x8*>(f0 + 2048 + ks * 512);
        }
    }
    for (int i = 0; i < GPS / 8; ++i) {   // 32 iters, 2 groups each
        {   // prefetch group g+4 into buffer B (always in-stripe)
            const f16* fn = PF + (size_t)(g + 4) * 4096 + lane * 8;
            #pragma unroll
            for (int ks = 0; ks < 4; ++ks) {
                HB[ks] = *reinterpret_cast<const f16x8*>(fn + ks * 512);
                LB[ks] = *reinterpret_cast<const f16x8*>(fn + 2048 + ks * 512);
            }
        }
        PROC(g, HA, LA);
        {   // prefetch group g+8 into buffer A (tail-guarded, re-reads g)
            int gp = (i + 1 < GPS / 8) ? g + 8 : g;
            const f16* fn = PF + (size_t)gp * 4096 + lane * 8;
            #pragma unroll
            for (int ks = 0; ks < 4; ++ks) {
                HA[ks] = *reinterpret_cast<const f16x8*>(fn + ks * 512);
                LA[ks] = *reinterpret_cast<const f16x8*>(fn + 2048 + ks * 512);
            }
        }
        PROC(g + 4, HB, LB);
        g += 8;
    }

    // Reduce across the hw bit (lanes l <-> l+32 share query col), tie -> lower idx.
    #pragma unroll
    for (int nt = 0; nt < 2; ++nt) {
        float sv = rmax[nt]; int iv = ridx[nt];
        float so = __shfl_xor(sv, 32);
        int   io = __shfl_xor(iv, 32);
        if (so > sv || (so == sv && io < iv)) { sv = so; iv = io; }
        if (hw == 0) {
            float s = -2.f * sv;                       // back to d^2-|x|^2 scale
            unsigned u = __float_as_uint(s);
            u = (u & 0x80000000u) ? ~u : (u | 0x80000000u);
            unsigned long long key = ((unsigned long long)u << 32) | (unsigned)iv;
            atomicMin(&best[qBase + nt * 32 + c32], key);
        }
    }
}

// Gather winning rows to out. 16 threads/query, coalesced float4 in/out.
__global__ __launch_bounds__(256) void gather_k(const unsigned long long* __restrict__ best,
                                                const float* __restrict__ P,
                                                float* __restrict__ out) {
    int g = blockIdx.x * 256 + threadIdx.x;  // NQ*16 threads
    int q = g >> 4, c = g & 15;
    unsigned idx = (unsigned)best[q];        // low 32 bits = index
    reinterpret_cast<float4*>(out)[g] =
        reinterpret_cast<const float4*>(P)[(size_t)idx * 16 + c];
}

extern "C" void kernel_launch(void* const* d_in, const int* in_sizes, int n_in,
                              void* d_out, int out_size, void* d_ws, size_t ws_size,
                              hipStream_t stream) {
    const float* X = (const float*)d_in[0];            // (4096, 64) f32
    const float* P = (const float*)d_in[1];            // (65536, 64) f32
    // d_in[2], d_in[3] unused by the reference output.
    float* out = (float*)d_out;                        // (4096, 64) f32

    // Workspace layout (all 16B-aligned):
    //   best @ 0           : NQ * 8 B        = 32 KB
    //   pnh  @ 32768       : MP * 4 B        = 256 KB   (0.5*|p|^2)
    //   XF   @ 294912      : NQ*DD*2*2 B     = 1 MB     (query frags hi/lo)
    //   PF   @ 1343488     : MP*DD*2*2 B     = 16 MB    (point frags hi/lo)
    unsigned long long* best = (unsigned long long*)d_ws;
    float* pnh = (float*)((char*)d_ws + 32768);
    f16*   XF  = (f16*)((char*)d_ws + 294912);
    f16*   PF  = (f16*)((char*)d_ws + 1343488);

    hipMemsetAsync(d_ws, 0xFF, NQ * sizeof(unsigned long long), stream);

    prep_k<<<(PG32 + XG32) / 4, 256, 0, stream>>>(P, X, PF, XF, pnh);

    argmin_k<<<(NQ / QT) * STRIPES, 256, 0, stream>>>(PF, XF, pnh, best);

    gather_k<<<NQ * 16 / 256, 256, 0, stream>>>(best, P, out);
}